// Round 30
// baseline (185.032 us; speedup 1.0000x reference)
//
#include <hip/hip_runtime.h>

// TransformerConvolution (graph attention with per-edge keys), MI355X gfx950.
// Rewrite: q_j . (edge_ij @ We_k) == edge_ij . (We_k^T q_j) = edge . qe_j
// -> 16x less per-edge work, no 268MB edge_k intermediate.
//
// R30: attn was latency-bound at 19.6% occupancy (512 blocks = 2/CU).
// Split j into 4 quarters -> 2048 blocks (8/CU, 100% occupancy cap),
// partial accumulators merged in the post kernel. float4 loads everywhere.

__device__ inline float guard_relu(float x) {
    if (x != x) return 0.0f;
    return fmaxf(x, 0.0f);
}

// ---------- Kernel 1: z@{Wq,Wk,Wv}, qe = We_k^T q  (256 blocks x 256) ------
__global__ void tc26_prep(
    const float* node, const float* hidden,
    const float* Wq, const float* Wk, const float* Wv, const float* Wek,
    float* qbuf, float* kbuf, float* vbuf, float* qebuf)
{
    __shared__ float z[4][128];
    __shared__ float qs[4][128];
    const int t = threadIdx.x;
    const int r0 = blockIdx.x * 4;            // global row = b*512 + n

    for (int kk = 0; kk < 2; ++kk) {
        int idx = t + kk * 256;               // 0..511
        int r = idx >> 7, c = idx & 127;
        int row = r0 + r;
        z[r][c] = (c < 64) ? node[row * 64 + c] : hidden[row * 64 + (c - 64)];
    }
    __syncthreads();

    const int o  = t & 127;
    const int rh = t >> 7;                    // rows rh and rh+2
    float aq0 = 0.f, aq1 = 0.f, ak0 = 0.f, ak1 = 0.f, av0 = 0.f, av1 = 0.f;
    for (int c = 0; c < 128; ++c) {
        float wq = Wq[c * 128 + o], wk = Wk[c * 128 + o], wv = Wv[c * 128 + o];
        float z0 = z[rh][c], z1 = z[rh + 2][c];
        aq0 = fmaf(z0, wq, aq0); aq1 = fmaf(z1, wq, aq1);
        ak0 = fmaf(z0, wk, ak0); ak1 = fmaf(z1, wk, ak1);
        av0 = fmaf(z0, wv, av0); av1 = fmaf(z1, wv, av1);
    }
    {
        int row0 = r0 + rh, row1 = r0 + rh + 2;
        qbuf[row0 * 128 + o] = aq0; qbuf[row1 * 128 + o] = aq1;
        kbuf[row0 * 128 + o] = ak0; kbuf[row1 * 128 + o] = ak1;
        vbuf[row0 * 128 + o] = av0; vbuf[row1 * 128 + o] = av1;
        qs[rh][o] = aq0; qs[rh + 2][o] = aq1;
    }
    __syncthreads();

    // qe[row][h][c] = sum_d q[row][h*16+d] * Wek[c*128 + h*16 + d]
    for (int kk = 0; kk < 2; ++kk) {
        int hc = t + kk * 256;                // 0..511
        int h = hc >> 6, c = hc & 63;
        for (int r = 0; r < 4; ++r) {
            float s = 0.f;
            for (int d = 0; d < 16; ++d)
                s = fmaf(qs[r][h * 16 + d], Wek[c * 128 + h * 16 + d], s);
            qebuf[((r0 + r) * 8 + h) * 64 + c] = s;
        }
    }
}

// ---------- Kernel 2: j-split attention partials (2048 blocks x 256) -------
// block = (b, i-pair, j-quarter). Scores for 2 rows x 128 j, then PV partial.
__global__ void tc26_attn(
    const float* edge, const float* adj,
    const float* qbuf, const float* kbuf, const float* vbuf,
    const float* qebuf, float* pacc, float* pden)
{
    __shared__ float qls[2][128];
    __shared__ float els[2][8][132];          // 528B row stride, 16B aligned
    const int t  = threadIdx.x;
    const int bid = blockIdx.x;
    const int jq = bid & 3;
    const int it = (bid >> 2) & 255;
    const int b  = bid >> 10;
    const int i0 = it * 2;
    const int ia = t & 1;                     // score phase: row
    const int ja = t >> 1;                    // score phase: j in tile (0..127)
    const int ip = t >> 7;                    // PV phase: row
    const int o  = t & 127;                   // PV phase: outdim (h*16+d)
    const int hB = o >> 4;

    qls[t >> 7][t & 127] = qbuf[(b * 512 + i0 + (t >> 7)) * 128 + (t & 127)];
    __syncthreads();

    const int j = jq * 128 + ja;
    // ---- scores for edge (i0+ia, j), all 8 heads; float4 loads ----
    const float* Erow  = edge  + ((size_t)(b * 512 + i0 + ia) * 512 + j) * 64;
    const float* qerow = qebuf + (size_t)(b * 512 + j) * 512;
    float s[8];
    #pragma unroll
    for (int h = 0; h < 8; ++h) s[h] = 0.f;
    #pragma unroll 4
    for (int cc = 0; cc < 16; ++cc) {
        float4 e4 = *(const float4*)(Erow + cc * 4);
        #pragma unroll
        for (int h = 0; h < 8; ++h) {
            float4 q4 = *(const float4*)(qerow + h * 64 + cc * 4);
            s[h] = fmaf(e4.x, q4.x, s[h]);
            s[h] = fmaf(e4.y, q4.y, s[h]);
            s[h] = fmaf(e4.z, q4.z, s[h]);
            s[h] = fmaf(e4.w, q4.w, s[h]);
        }
    }
    const float* krow = kbuf + (size_t)(b * 512 + j) * 128;
    #pragma unroll
    for (int h = 0; h < 8; ++h) {
        float qk = 0.f;
        #pragma unroll
        for (int dd = 0; dd < 4; ++dd) {
            float4 k4 = *(const float4*)(krow + h * 16 + dd * 4);
            float4 q4 = *(const float4*)(&qls[ia][h * 16 + dd * 4]);
            qk = fmaf(k4.x, q4.x, qk);
            qk = fmaf(k4.y, q4.y, qk);
            qk = fmaf(k4.z, q4.z, qk);
            qk = fmaf(k4.w, q4.w, qk);
        }
        s[h] += qk;
    }
    const float am = adj[(size_t)(b * 512 + i0 + ia) * 512 + j];
    #pragma unroll
    for (int h = 0; h < 8; ++h)
        els[ia][h][ja] = am * __expf(s[h] * 0.25f);
    __syncthreads();

    // ---- PV partial + denominator over this j-quarter ----
    const float* vbase = vbuf + (size_t)(b * 512 + jq * 128) * 128 + o;
    const float4* erow4 = (const float4*)(&els[ip][hB][0]);
    float acc = 0.f, dacc = 0.f;
    #pragma unroll 8
    for (int j4 = 0; j4 < 32; ++j4) {
        float4 e4 = erow4[j4];
        float v0 = vbase[(j4 * 4 + 0) * 128];
        float v1 = vbase[(j4 * 4 + 1) * 128];
        float v2 = vbase[(j4 * 4 + 2) * 128];
        float v3 = vbase[(j4 * 4 + 3) * 128];
        acc = fmaf(e4.x, v0, acc); dacc += e4.x;
        acc = fmaf(e4.y, v1, acc); dacc += e4.y;
        acc = fmaf(e4.z, v2, acc); dacc += e4.z;
        acc = fmaf(e4.w, v3, acc); dacc += e4.w;
    }
    const size_t idx = ((size_t)(b * 512 + i0 + ip) * 4 + jq) * 128 + o;
    pacc[idx] = acc;
    pden[idx] = dacc;
}

// ---------- Kernel 3: merge quarters + Wo + FFN, f32 store -----------------
__global__ void tc26_post(
    const float* pacc, const float* pden,
    const float* Wo, const float* W1,
    const float* b1f, const float* W2, const float* b2f,
    float* __restrict__ out)
{
    __shared__ float a[4][128];
    __shared__ float y[4][128];
    const int t = threadIdx.x;
    const int o = t & 127, rh = t >> 7;
    const int r0 = blockIdx.x * 4;

    for (int m = 0; m < 2; ++m) {
        int r = rh + 2 * m;
        int row = r0 + r;
        float s = 0.f, d = 0.f;
        #pragma unroll
        for (int q = 0; q < 4; ++q) {
            size_t idx = ((size_t)row * 4 + q) * 128 + o;
            s += pacc[idx];
            d += pden[idx];
        }
        a[r][o] = s / d;                       // adj self-loops -> d > 0
    }
    __syncthreads();

    float acc0 = 0.f, acc1 = 0.f;
    for (int c = 0; c < 128; ++c) {
        float w = Wo[c * 128 + o];
        acc0 = fmaf(a[rh][c], w, acc0);
        acc1 = fmaf(a[rh + 2][c], w, acc1);
    }
    y[rh][o] = acc0; y[rh + 2][o] = acc1;
    __syncthreads();

    acc0 = 0.f; acc1 = 0.f;
    for (int c = 0; c < 128; ++c) {
        float w = W1[c * 128 + o];
        acc0 = fmaf(y[rh][c], w, acc0);
        acc1 = fmaf(y[rh + 2][c], w, acc1);
    }
    float bb = b1f[o];
    __syncthreads();
    a[rh][o]     = guard_relu(acc0 + bb);
    a[rh + 2][o] = guard_relu(acc1 + bb);
    __syncthreads();

    acc0 = 0.f; acc1 = 0.f;
    for (int c = 0; c < 128; ++c) {
        float w = W2[c * 128 + o];
        acc0 = fmaf(a[rh][c], w, acc0);
        acc1 = fmaf(a[rh + 2][c], w, acc1);
    }
    float bb2 = b2f[o];
    int row0 = r0 + rh, row1 = r0 + rh + 2;
    out[row0 * 128 + o] = guard_relu(acc0 + bb2);   // FLOAT32 store
    out[row1 * 128 + o] = guard_relu(acc1 + bb2);
}

extern "C" void kernel_launch(void* const* d_in, const int* in_sizes, int n_in,
                              void* d_out, int out_size, void* d_ws, size_t ws_size,
                              hipStream_t stream) {
    (void)in_sizes; (void)n_in; (void)out_size; (void)ws_size;

    const float* node   = (const float*)d_in[0];
    const float* edge   = (const float*)d_in[1];
    const float* hidden = (const float*)d_in[3];   // d_in[2] = graph_fts, unused
    const float* adj    = (const float*)d_in[4];
    const float* Wq     = (const float*)d_in[5];
    const float* Wk     = (const float*)d_in[6];
    const float* Wv     = (const float*)d_in[7];
    const float* Wo     = (const float*)d_in[8];
    const float* Wek    = (const float*)d_in[9];
    const float* W1     = (const float*)d_in[10];
    const float* b1f    = (const float*)d_in[11];
    const float* W2     = (const float*)d_in[12];
    const float* b2f    = (const float*)d_in[13];
    float* out = (float*)d_out;                    // reference output is f32

    float* ws    = (float*)d_ws;
    float* qbuf  = ws;                 // 131072 f32
    float* kbuf  = qbuf  + 131072;     // 131072
    float* vbuf  = kbuf  + 131072;     // 131072
    float* qebuf = vbuf  + 131072;     // 524288  qe[b][j][h][c]
    float* pacc  = qebuf + 524288;     // 524288  [row][jq][128]
    float* pden  = pacc  + 524288;     // 524288  [row][jq][128]
    // total ~9.4 MB workspace (all regions fully written before read)

    tc26_prep<<<256, 256, 0, stream>>>(node, hidden, Wq, Wk, Wv, Wek,
                                       qbuf, kbuf, vbuf, qebuf);
    tc26_attn<<<2048, 256, 0, stream>>>(edge, adj, qbuf, kbuf, vbuf, qebuf,
                                        pacc, pden);
    tc26_post<<<256, 256, 0, stream>>>(pacc, pden, Wo, W1, b1f, W2, b2f, out);
}

// Round 31
// 80.264 us; speedup vs baseline: 2.3053x; 2.3053x over previous
//
#include <hip/hip_runtime.h>

// TransformerConvolution (graph attention with per-edge keys), MI355X gfx950.
// Rewrite: q_j . (edge_ij @ We_k) == edge_ij . (We_k^T q_j) = edge . qe_j
//
// R31: score phase was memory-TRANSACTION-bound (per-lane-private row reads:
// ~32-64 cache lines per wave load instr; VALU 9%, HBM 7%, dur flat vs
// occupancy). Restructure: 8-lane groups own the contiguous c-axis ->
// all loads coalesced (128B/group segments); 3-step shfl_xor butterfly
// finishes the c-sum. qe/k loads amortized over 4 i-rows per block.

__device__ inline float guard_relu(float x) {
    if (x != x) return 0.0f;
    return fmaxf(x, 0.0f);
}

// ---------- Kernel 1: z@{Wq,Wk,Wv}, qe = We_k^T q  (256 blocks x 256) ------
__global__ void tc27_prep(
    const float* node, const float* hidden,
    const float* Wq, const float* Wk, const float* Wv, const float* Wek,
    float* qbuf, float* kbuf, float* vbuf, float* qebuf)
{
    __shared__ float z[4][128];
    __shared__ float qs[4][128];
    const int t = threadIdx.x;
    const int r0 = blockIdx.x * 4;            // global row = b*512 + n

    for (int kk = 0; kk < 2; ++kk) {
        int idx = t + kk * 256;               // 0..511
        int r = idx >> 7, c = idx & 127;
        int row = r0 + r;
        z[r][c] = (c < 64) ? node[row * 64 + c] : hidden[row * 64 + (c - 64)];
    }
    __syncthreads();

    const int o  = t & 127;
    const int rh = t >> 7;                    // rows rh and rh+2
    float aq0 = 0.f, aq1 = 0.f, ak0 = 0.f, ak1 = 0.f, av0 = 0.f, av1 = 0.f;
    for (int c = 0; c < 128; ++c) {
        float wq = Wq[c * 128 + o], wk = Wk[c * 128 + o], wv = Wv[c * 128 + o];
        float z0 = z[rh][c], z1 = z[rh + 2][c];
        aq0 = fmaf(z0, wq, aq0); aq1 = fmaf(z1, wq, aq1);
        ak0 = fmaf(z0, wk, ak0); ak1 = fmaf(z1, wk, ak1);
        av0 = fmaf(z0, wv, av0); av1 = fmaf(z1, wv, av1);
    }
    {
        int row0 = r0 + rh, row1 = r0 + rh + 2;
        qbuf[row0 * 128 + o] = aq0; qbuf[row1 * 128 + o] = aq1;
        kbuf[row0 * 128 + o] = ak0; kbuf[row1 * 128 + o] = ak1;
        vbuf[row0 * 128 + o] = av0; vbuf[row1 * 128 + o] = av1;
        qs[rh][o] = aq0; qs[rh + 2][o] = aq1;
    }
    __syncthreads();

    // qe[row][h][c] = sum_d q[row][h*16+d] * Wek[c*128 + h*16 + d]
    for (int kk = 0; kk < 2; ++kk) {
        int hc = t + kk * 256;                // 0..511
        int h = hc >> 6, c = hc & 63;
        for (int r = 0; r < 4; ++r) {
            float s = 0.f;
            for (int d = 0; d < 16; ++d)
                s = fmaf(qs[r][h * 16 + d], Wek[c * 128 + h * 16 + d], s);
            qebuf[((r0 + r) * 8 + h) * 64 + c] = s;
        }
    }
}

// ---------- Kernel 2: coalesced group-score attention (2048 blocks x 256) --
// block = (b, i-quad(4 rows), j-chunk of 64). 32 groups x 8 lanes: lane owns
// c-chunk -> all global loads coalesced; shfl_xor butterfly sums over c.
__global__ void tc27_attn(
    const float* edge, const float* adj,
    const float* qbuf, const float* kbuf, const float* vbuf,
    const float* qebuf, float* pacc, float* pden)
{
    __shared__ float qls[4][132];
    __shared__ float els[4][8][66];
    const int t   = threadIdx.x;
    const int bid = blockIdx.x;
    const int jq  = bid & 7;                  // 8 chunks of 64 j
    const int it  = (bid >> 3) & 127;         // i-quad
    const int b   = bid >> 10;
    const int i0  = it * 4;

    for (int kk = 0; kk < 2; ++kk) {
        int idx = t + kk * 256;               // 0..511
        int r = idx >> 7, c = idx & 127;
        qls[r][c] = qbuf[(size_t)(b * 512 + i0 + r) * 128 + c];
    }
    __syncthreads();

    const int g = t >> 3;                     // group 0..31
    const int l = t & 7;                      // lane in group

    for (int u = 0; u < 2; ++u) {
        const int jl = g + u * 32;            // groups cover contiguous j
        const int j  = jq * 64 + jl;
        const float* er0 = edge + ((size_t)(b * 512 + i0) * 512 + j) * 64 + l * 8;
        float4 ea[4], eb[4];
        #pragma unroll
        for (int r = 0; r < 4; ++r) {
            const float* er = er0 + (size_t)r * 512 * 64;
            ea[r] = *(const float4*)(er);
            eb[r] = *(const float4*)(er + 4);
        }
        float am[4];
        #pragma unroll
        for (int r = 0; r < 4; ++r)
            am[r] = adj[(size_t)(b * 512 + i0 + r) * 512 + j];
        const float* qerow = qebuf + (size_t)(b * 512 + j) * 512 + l * 8;
        const float* krow  = kbuf  + (size_t)(b * 512 + j) * 128;

        #pragma unroll
        for (int h = 0; h < 8; ++h) {
            float4 qa = *(const float4*)(qerow + h * 64);
            float4 qb = *(const float4*)(qerow + h * 64 + 4);
            float k0 = krow[h * 16 + l];
            float k1 = krow[h * 16 + 8 + l];
            float q0 = qls[0][h * 16 + l], q0b = qls[0][h * 16 + 8 + l];
            float q1 = qls[1][h * 16 + l], q1b = qls[1][h * 16 + 8 + l];
            float q2 = qls[2][h * 16 + l], q2b = qls[2][h * 16 + 8 + l];
            float q3 = qls[3][h * 16 + l], q3b = qls[3][h * 16 + 8 + l];
            float p[4];
            p[0] = ea[0].x*qa.x + ea[0].y*qa.y + ea[0].z*qa.z + ea[0].w*qa.w
                 + eb[0].x*qb.x + eb[0].y*qb.y + eb[0].z*qb.z + eb[0].w*qb.w
                 + k0 * q0 + k1 * q0b;
            p[1] = ea[1].x*qa.x + ea[1].y*qa.y + ea[1].z*qa.z + ea[1].w*qa.w
                 + eb[1].x*qb.x + eb[1].y*qb.y + eb[1].z*qb.z + eb[1].w*qb.w
                 + k0 * q1 + k1 * q1b;
            p[2] = ea[2].x*qa.x + ea[2].y*qa.y + ea[2].z*qa.z + ea[2].w*qa.w
                 + eb[2].x*qb.x + eb[2].y*qb.y + eb[2].z*qb.z + eb[2].w*qb.w
                 + k0 * q2 + k1 * q2b;
            p[3] = ea[3].x*qa.x + ea[3].y*qa.y + ea[3].z*qa.z + ea[3].w*qa.w
                 + eb[3].x*qb.x + eb[3].y*qb.y + eb[3].z*qb.z + eb[3].w*qb.w
                 + k0 * q3 + k1 * q3b;
            #pragma unroll
            for (int m = 4; m >= 1; m >>= 1) {
                #pragma unroll
                for (int r = 0; r < 4; ++r)
                    p[r] += __shfl_xor(p[r], m, 64);   // stays in 8-lane group
            }
            if (l == h) {
                #pragma unroll
                for (int r = 0; r < 4; ++r)
                    els[r][h][jl] = am[r] * __expf(p[r] * 0.25f);
            }
        }
    }
    __syncthreads();

    // ---- PV partials over this 64-j chunk ----
    const int o  = t & 127;                   // outdim (h*16+d)
    const int ip = t >> 7;                    // rows ip, ip+2
    const int hB = o >> 4;
    const float* vbase = vbuf + ((size_t)(b * 512) + jq * 64) * 128 + o;
    float acc0 = 0.f, acc1 = 0.f, d0 = 0.f, d1 = 0.f;
    #pragma unroll 8
    for (int jl = 0; jl < 64; ++jl) {
        float v  = vbase[(size_t)jl * 128];
        float e0 = els[ip][hB][jl];
        float e1 = els[ip + 2][hB][jl];
        acc0 = fmaf(e0, v, acc0); d0 += e0;
        acc1 = fmaf(e1, v, acc1); d1 += e1;
    }
    size_t ix0 = ((size_t)(b * 512 + i0 + ip) * 8 + jq) * 128 + o;
    size_t ix1 = ((size_t)(b * 512 + i0 + ip + 2) * 8 + jq) * 128 + o;
    pacc[ix0] = acc0; pden[ix0] = d0;
    pacc[ix1] = acc1; pden[ix1] = d1;
}

// ---------- Kernel 3: merge 8 chunks + Wo + FFN, f32 store -----------------
__global__ void tc27_post(
    const float* pacc, const float* pden,
    const float* Wo, const float* W1,
    const float* b1f, const float* W2, const float* b2f,
    float* __restrict__ out)
{
    __shared__ float a[4][128];
    __shared__ float y[4][128];
    const int t = threadIdx.x;
    const int o = t & 127, rh = t >> 7;
    const int r0 = blockIdx.x * 4;

    for (int m = 0; m < 2; ++m) {
        int r = rh + 2 * m;
        int row = r0 + r;
        float s = 0.f, d = 0.f;
        #pragma unroll
        for (int q = 0; q < 8; ++q) {
            size_t idx = ((size_t)row * 8 + q) * 128 + o;
            s += pacc[idx];
            d += pden[idx];
        }
        a[r][o] = s / d;                       // adj self-loops -> d > 0
    }
    __syncthreads();

    float acc0 = 0.f, acc1 = 0.f;
    for (int c = 0; c < 128; ++c) {
        float w = Wo[c * 128 + o];
        acc0 = fmaf(a[rh][c], w, acc0);
        acc1 = fmaf(a[rh + 2][c], w, acc1);
    }
    y[rh][o] = acc0; y[rh + 2][o] = acc1;
    __syncthreads();

    acc0 = 0.f; acc1 = 0.f;
    for (int c = 0; c < 128; ++c) {
        float w = W1[c * 128 + o];
        acc0 = fmaf(y[rh][c], w, acc0);
        acc1 = fmaf(y[rh + 2][c], w, acc1);
    }
    float bb = b1f[o];
    __syncthreads();
    a[rh][o]     = guard_relu(acc0 + bb);
    a[rh + 2][o] = guard_relu(acc1 + bb);
    __syncthreads();

    acc0 = 0.f; acc1 = 0.f;
    for (int c = 0; c < 128; ++c) {
        float w = W2[c * 128 + o];
        acc0 = fmaf(a[rh][c], w, acc0);
        acc1 = fmaf(a[rh + 2][c], w, acc1);
    }
    float bb2 = b2f[o];
    int row0 = r0 + rh, row1 = r0 + rh + 2;
    out[row0 * 128 + o] = guard_relu(acc0 + bb2);   // FLOAT32 store
    out[row1 * 128 + o] = guard_relu(acc1 + bb2);
}

extern "C" void kernel_launch(void* const* d_in, const int* in_sizes, int n_in,
                              void* d_out, int out_size, void* d_ws, size_t ws_size,
                              hipStream_t stream) {
    (void)in_sizes; (void)n_in; (void)out_size; (void)ws_size;

    const float* node   = (const float*)d_in[0];
    const float* edge   = (const float*)d_in[1];
    const float* hidden = (const float*)d_in[3];   // d_in[2] = graph_fts, unused
    const float* adj    = (const float*)d_in[4];
    const float* Wq     = (const float*)d_in[5];
    const float* Wk     = (const float*)d_in[6];
    const float* Wv     = (const float*)d_in[7];
    const float* Wo     = (const float*)d_in[8];
    const float* Wek    = (const float*)d_in[9];
    const float* W1     = (const float*)d_in[10];
    const float* b1f    = (const float*)d_in[11];
    const float* W2     = (const float*)d_in[12];
    const float* b2f    = (const float*)d_in[13];
    float* out = (float*)d_out;                    // reference output is f32

    float* ws    = (float*)d_ws;
    float* qbuf  = ws;                 // 131072 f32
    float* kbuf  = qbuf  + 131072;     // 131072
    float* vbuf  = kbuf  + 131072;     // 131072
    float* qebuf = vbuf  + 131072;     // 524288  qe[b][j][h][c]
    float* pacc  = qebuf + 524288;     // 1048576 [row][jq8][128]
    float* pden  = pacc  + 1048576;    // 1048576
    // total ~11.5 MB workspace (all regions fully written before read)

    tc27_prep<<<256, 256, 0, stream>>>(node, hidden, Wq, Wk, Wv, Wek,
                                       qbuf, kbuf, vbuf, qebuf);
    tc27_attn<<<2048, 256, 0, stream>>>(edge, adj, qbuf, kbuf, vbuf, qebuf,
                                        pacc, pden);
    tc27_post<<<256, 256, 0, stream>>>(pacc, pden, Wo, W1, b1f, W2, b2f, out);
}

// Round 32
// 78.521 us; speedup vs baseline: 2.3565x; 1.0222x over previous
//
#include <hip/hip_runtime.h>

// TransformerConvolution (graph attention with per-edge keys), MI355X gfx950.
// Rewrite: q_j . (edge_ij @ We_k) == edge_ij . (We_k^T q_j) = edge . qe_j
//
// R32: R31 fixed coalescing (conflicts 0, 950 GB/s) but each thread
// serialized two score phases -> memory pipe idle during compute.
// Interleave both j-phases in registers: all loads issued upfront,
// two independent FMA+butterfly chains (2x ILP, 2x outstanding loads).

__device__ inline float guard_relu(float x) {
    if (x != x) return 0.0f;
    return fmaxf(x, 0.0f);
}

// ---------- Kernel 1: z@{Wq,Wk,Wv}, qe = We_k^T q  (256 blocks x 256) ------
__global__ void tc28_prep(
    const float* node, const float* hidden,
    const float* Wq, const float* Wk, const float* Wv, const float* Wek,
    float* qbuf, float* kbuf, float* vbuf, float* qebuf)
{
    __shared__ float z[4][128];
    __shared__ float qs[4][128];
    const int t = threadIdx.x;
    const int r0 = blockIdx.x * 4;            // global row = b*512 + n

    for (int kk = 0; kk < 2; ++kk) {
        int idx = t + kk * 256;               // 0..511
        int r = idx >> 7, c = idx & 127;
        int row = r0 + r;
        z[r][c] = (c < 64) ? node[row * 64 + c] : hidden[row * 64 + (c - 64)];
    }
    __syncthreads();

    const int o  = t & 127;
    const int rh = t >> 7;                    // rows rh and rh+2
    float aq0 = 0.f, aq1 = 0.f, ak0 = 0.f, ak1 = 0.f, av0 = 0.f, av1 = 0.f;
    for (int c = 0; c < 128; ++c) {
        float wq = Wq[c * 128 + o], wk = Wk[c * 128 + o], wv = Wv[c * 128 + o];
        float z0 = z[rh][c], z1 = z[rh + 2][c];
        aq0 = fmaf(z0, wq, aq0); aq1 = fmaf(z1, wq, aq1);
        ak0 = fmaf(z0, wk, ak0); ak1 = fmaf(z1, wk, ak1);
        av0 = fmaf(z0, wv, av0); av1 = fmaf(z1, wv, av1);
    }
    {
        int row0 = r0 + rh, row1 = r0 + rh + 2;
        qbuf[row0 * 128 + o] = aq0; qbuf[row1 * 128 + o] = aq1;
        kbuf[row0 * 128 + o] = ak0; kbuf[row1 * 128 + o] = ak1;
        vbuf[row0 * 128 + o] = av0; vbuf[row1 * 128 + o] = av1;
        qs[rh][o] = aq0; qs[rh + 2][o] = aq1;
    }
    __syncthreads();

    // qe[row][h][c] = sum_d q[row][h*16+d] * Wek[c*128 + h*16 + d]
    for (int kk = 0; kk < 2; ++kk) {
        int hc = t + kk * 256;                // 0..511
        int h = hc >> 6, c = hc & 63;
        for (int r = 0; r < 4; ++r) {
            float s = 0.f;
            for (int d = 0; d < 16; ++d)
                s = fmaf(qs[r][h * 16 + d], Wek[c * 128 + h * 16 + d], s);
            qebuf[((r0 + r) * 8 + h) * 64 + c] = s;
        }
    }
}

// ---------- Kernel 2: dual-j interleaved score attention (2048 x 256) ------
// block = (b, i-quad(4 rows), j-chunk of 64). 32 groups x 8 lanes; each
// group handles j0=g and j1=g+32 simultaneously (2x ILP / outstanding loads).
__global__ void tc28_attn(
    const float* edge, const float* adj,
    const float* qbuf, const float* kbuf, const float* vbuf,
    const float* qebuf, float* pacc, float* pden)
{
    __shared__ float qls[4][132];
    __shared__ float els[4][8][66];
    const int t   = threadIdx.x;
    const int bid = blockIdx.x;
    const int jq  = bid & 7;                  // 8 chunks of 64 j
    const int it  = (bid >> 3) & 127;         // i-quad
    const int b   = bid >> 10;
    const int i0  = it * 4;

    for (int kk = 0; kk < 2; ++kk) {
        int idx = t + kk * 256;               // 0..511
        int r = idx >> 7, c = idx & 127;
        qls[r][c] = qbuf[(size_t)(b * 512 + i0 + r) * 128 + c];
    }
    __syncthreads();

    const int g = t >> 3;                     // group 0..31
    const int l = t & 7;                      // lane in group

    const int jl0 = g, jl1 = g + 32;
    const int j0 = jq * 64 + jl0;
    const int j1 = jq * 64 + jl1;

    // ---- issue ALL loads for both j's upfront ----
    const float* e00 = edge + ((size_t)(b * 512 + i0) * 512 + j0) * 64 + l * 8;
    const float* e10 = edge + ((size_t)(b * 512 + i0) * 512 + j1) * 64 + l * 8;
    float4 ea0[4], eb0[4], ea1[4], eb1[4];
    #pragma unroll
    for (int r = 0; r < 4; ++r) {
        const float* p0 = e00 + (size_t)r * 512 * 64;
        const float* p1 = e10 + (size_t)r * 512 * 64;
        ea0[r] = *(const float4*)(p0);
        eb0[r] = *(const float4*)(p0 + 4);
        ea1[r] = *(const float4*)(p1);
        eb1[r] = *(const float4*)(p1 + 4);
    }
    float am0[4], am1[4];
    #pragma unroll
    for (int r = 0; r < 4; ++r) {
        am0[r] = adj[(size_t)(b * 512 + i0 + r) * 512 + j0];
        am1[r] = adj[(size_t)(b * 512 + i0 + r) * 512 + j1];
    }
    const float* qer0 = qebuf + (size_t)(b * 512 + j0) * 512 + l * 8;
    const float* qer1 = qebuf + (size_t)(b * 512 + j1) * 512 + l * 8;
    const float* kr0  = kbuf  + (size_t)(b * 512 + j0) * 128;
    const float* kr1  = kbuf  + (size_t)(b * 512 + j1) * 128;

    #pragma unroll
    for (int h = 0; h < 8; ++h) {
        float4 qa0 = *(const float4*)(qer0 + h * 64);
        float4 qb0 = *(const float4*)(qer0 + h * 64 + 4);
        float4 qa1 = *(const float4*)(qer1 + h * 64);
        float4 qb1 = *(const float4*)(qer1 + h * 64 + 4);
        float k00 = kr0[h * 16 + l], k01 = kr0[h * 16 + 8 + l];
        float k10 = kr1[h * 16 + l], k11 = kr1[h * 16 + 8 + l];
        float p0[4], p1[4];
        #pragma unroll
        for (int r = 0; r < 4; ++r) {
            float qv  = qls[r][h * 16 + l];
            float qvb = qls[r][h * 16 + 8 + l];
            p0[r] = ea0[r].x*qa0.x + ea0[r].y*qa0.y + ea0[r].z*qa0.z + ea0[r].w*qa0.w
                  + eb0[r].x*qb0.x + eb0[r].y*qb0.y + eb0[r].z*qb0.z + eb0[r].w*qb0.w
                  + k00 * qv + k01 * qvb;
            p1[r] = ea1[r].x*qa1.x + ea1[r].y*qa1.y + ea1[r].z*qa1.z + ea1[r].w*qa1.w
                  + eb1[r].x*qb1.x + eb1[r].y*qb1.y + eb1[r].z*qb1.z + eb1[r].w*qb1.w
                  + k10 * qv + k11 * qvb;
        }
        #pragma unroll
        for (int m = 4; m >= 1; m >>= 1) {
            #pragma unroll
            for (int r = 0; r < 4; ++r) {
                p0[r] += __shfl_xor(p0[r], m, 64);   // two independent chains
                p1[r] += __shfl_xor(p1[r], m, 64);
            }
        }
        if (l == h) {
            #pragma unroll
            for (int r = 0; r < 4; ++r) {
                els[r][h][jl0] = am0[r] * __expf(p0[r] * 0.25f);
                els[r][h][jl1] = am1[r] * __expf(p1[r] * 0.25f);
            }
        }
    }
    __syncthreads();

    // ---- PV partials over this 64-j chunk ----
    const int o  = t & 127;                   // outdim (h*16+d)
    const int ip = t >> 7;                    // rows ip, ip+2
    const int hB = o >> 4;
    const float* vbase = vbuf + ((size_t)(b * 512) + jq * 64) * 128 + o;
    float acc0 = 0.f, acc1 = 0.f, d0 = 0.f, d1 = 0.f;
    #pragma unroll 8
    for (int jl = 0; jl < 64; ++jl) {
        float v  = vbase[(size_t)jl * 128];
        float e0 = els[ip][hB][jl];
        float e1 = els[ip + 2][hB][jl];
        acc0 = fmaf(e0, v, acc0); d0 += e0;
        acc1 = fmaf(e1, v, acc1); d1 += e1;
    }
    size_t ix0 = ((size_t)(b * 512 + i0 + ip) * 8 + jq) * 128 + o;
    size_t ix1 = ((size_t)(b * 512 + i0 + ip + 2) * 8 + jq) * 128 + o;
    pacc[ix0] = acc0; pden[ix0] = d0;
    pacc[ix1] = acc1; pden[ix1] = d1;
}

// ---------- Kernel 3: merge 8 chunks + Wo + FFN, f32 store -----------------
__global__ void tc28_post(
    const float* pacc, const float* pden,
    const float* Wo, const float* W1,
    const float* b1f, const float* W2, const float* b2f,
    float* __restrict__ out)
{
    __shared__ float a[4][128];
    __shared__ float y[4][128];
    const int t = threadIdx.x;
    const int o = t & 127, rh = t >> 7;
    const int r0 = blockIdx.x * 4;

    for (int m = 0; m < 2; ++m) {
        int r = rh + 2 * m;
        int row = r0 + r;
        float s = 0.f, d = 0.f;
        #pragma unroll
        for (int q = 0; q < 8; ++q) {
            size_t idx = ((size_t)row * 8 + q) * 128 + o;
            s += pacc[idx];
            d += pden[idx];
        }
        a[r][o] = s / d;                       // adj self-loops -> d > 0
    }
    __syncthreads();

    float acc0 = 0.f, acc1 = 0.f;
    for (int c = 0; c < 128; ++c) {
        float w = Wo[c * 128 + o];
        acc0 = fmaf(a[rh][c], w, acc0);
        acc1 = fmaf(a[rh + 2][c], w, acc1);
    }
    y[rh][o] = acc0; y[rh + 2][o] = acc1;
    __syncthreads();

    acc0 = 0.f; acc1 = 0.f;
    for (int c = 0; c < 128; ++c) {
        float w = W1[c * 128 + o];
        acc0 = fmaf(y[rh][c], w, acc0);
        acc1 = fmaf(y[rh + 2][c], w, acc1);
    }
    float bb = b1f[o];
    __syncthreads();
    a[rh][o]     = guard_relu(acc0 + bb);
    a[rh + 2][o] = guard_relu(acc1 + bb);
    __syncthreads();

    acc0 = 0.f; acc1 = 0.f;
    for (int c = 0; c < 128; ++c) {
        float w = W2[c * 128 + o];
        acc0 = fmaf(a[rh][c], w, acc0);
        acc1 = fmaf(a[rh + 2][c], w, acc1);
    }
    float bb2 = b2f[o];
    int row0 = r0 + rh, row1 = r0 + rh + 2;
    out[row0 * 128 + o] = guard_relu(acc0 + bb2);   // FLOAT32 store
    out[row1 * 128 + o] = guard_relu(acc1 + bb2);
}

extern "C" void kernel_launch(void* const* d_in, const int* in_sizes, int n_in,
                              void* d_out, int out_size, void* d_ws, size_t ws_size,
                              hipStream_t stream) {
    (void)in_sizes; (void)n_in; (void)out_size; (void)ws_size;

    const float* node   = (const float*)d_in[0];
    const float* edge   = (const float*)d_in[1];
    const float* hidden = (const float*)d_in[3];   // d_in[2] = graph_fts, unused
    const float* adj    = (const float*)d_in[4];
    const float* Wq     = (const float*)d_in[5];
    const float* Wk     = (const float*)d_in[6];
    const float* Wv     = (const float*)d_in[7];
    const float* Wo     = (const float*)d_in[8];
    const float* Wek    = (const float*)d_in[9];
    const float* W1     = (const float*)d_in[10];
    const float* b1f    = (const float*)d_in[11];
    const float* W2     = (const float*)d_in[12];
    const float* b2f    = (const float*)d_in[13];
    float* out = (float*)d_out;                    // reference output is f32

    float* ws    = (float*)d_ws;
    float* qbuf  = ws;                 // 131072 f32
    float* kbuf  = qbuf  + 131072;     // 131072
    float* vbuf  = kbuf  + 131072;     // 131072
    float* qebuf = vbuf  + 131072;     // 524288  qe[b][j][h][c]
    float* pacc  = qebuf + 524288;     // 1048576 [row][jq8][128]
    float* pden  = pacc  + 1048576;    // 1048576
    // total ~11.5 MB workspace (all regions fully written before read)

    tc28_prep<<<256, 256, 0, stream>>>(node, hidden, Wq, Wk, Wv, Wek,
                                       qbuf, kbuf, vbuf, qebuf);
    tc28_attn<<<2048, 256, 0, stream>>>(edge, adj, qbuf, kbuf, vbuf, qebuf,
                                        pacc, pden);
    tc28_post<<<256, 256, 0, stream>>>(pacc, pden, Wo, W1, b1f, W2, b2f, out);
}